// Round 4
// baseline (315.605 us; speedup 1.0000x reference)
//
#include <hip/hip_runtime.h>
#include <math.h>

// Problem constants
#define B_   8
#define L_   256
#define C_   512
#define OUT_ 512
#define NB   512      // 2 blocks/CU guaranteed resident (LB(512,4) -> <=128 VGPR)
#define NT   512

typedef _Float16 half8 __attribute__((ext_vector_type(8)));
typedef _Float16 half4 __attribute__((ext_vector_type(4)));
typedef float    f32x4 __attribute__((ext_vector_type(4)));
typedef float    f32x2 __attribute__((ext_vector_type(2)));

// ---------------------------------------------------------------------------
// Persistent mega-kernel, 2 dispatches total (64B memset + this).
// vs R3: ALL float atomics removed (they were both the 538us hotspot --
// ~2048 serialized agent-scope RMWs per cache line -- and the replay
// nondeterminism). Every global value now has exactly one writer and all
// reductions run in fixed order. Barrier = integer counter only.
// ---------------------------------------------------------------------------

struct SmemA { _Float16 tr[64][80]; };                                   // 10240 B
struct SmemC { float red[8][256]; float ws[2][16][20]; float wred[8]; }; // 10784 B
struct SmemD { float cp[C_]; float redf[NT]; };                          //  4096 B
union __align__(16) SmemU { SmemA a; SmemC c; SmemD d; };

__device__ __forceinline__ float sigmoid_fast(float z) {
    float e = __builtin_amdgcn_exp2f(-1.4426950408889634f * z);
    return __builtin_amdgcn_rcpf(e + 1.0f);
}

// Grid barrier: per-phase counter slot, zeroed by the 64B memset each launch.
// Release: __threadfence (agent fence -> L2 writeback across XCDs);
// Acquire: agent-scope atomic load. Functionally verified in R3 (first-run
// correctness passed); only the float-atomic accumulation was broken.
__device__ __forceinline__ void grid_barrier(unsigned* __restrict__ bar, int k) {
    __syncthreads();
    if (threadIdx.x == 0) {
        __threadfence();
        unsigned arrived = __hip_atomic_fetch_add(&bar[k], 1u, __ATOMIC_ACQ_REL,
                                                  __HIP_MEMORY_SCOPE_AGENT) + 1u;
        if (arrived < (unsigned)NB) {
            while (__hip_atomic_load(&bar[k], __ATOMIC_ACQUIRE,
                                     __HIP_MEMORY_SCOPE_AGENT) < (unsigned)NB)
                __builtin_amdgcn_s_sleep(8);
        }
    }
    __syncthreads();
}

__global__ __launch_bounds__(NT, 4)
void mega_kernel(const float* __restrict__ xd, const float* __restrict__ xt,
                 const float* __restrict__ Wc, const float* __restrict__ bc,
                 const float* __restrict__ Wp, const float* __restrict__ bp,
                 const float* __restrict__ Wf, const float* __restrict__ bfv,
                 unsigned* __restrict__ bar,
                 _Float16* __restrict__ Xth, _Float16* __restrict__ Xdh,
                 _Float16* __restrict__ Wpt, _Float16* __restrict__ Wct,
                 _Float16* __restrict__ pt, _Float16* __restrict__ pc,
                 float* __restrict__ cpart, float* __restrict__ tile_sum,
                 float* __restrict__ out)
{
    __shared__ SmemU sm;
    const int bid  = blockIdx.x;
    const int tid  = threadIdx.x;
    const int wv   = tid >> 6, lane = tid & 63;
    const int l15  = lane & 15, quad = lane >> 4;

    // ============ Phase A: relu-cvt X (all blocks, 2 f4/thread) + W^T (128) =
    {
        const int r = bid * NT + tid;                 // 0..262143 float4 index
        const float4 v1 = ((const float4*)xt)[r];
        half4 h1;
        h1[0] = (_Float16)fmaxf(v1.x, 0.f); h1[1] = (_Float16)fmaxf(v1.y, 0.f);
        h1[2] = (_Float16)fmaxf(v1.z, 0.f); h1[3] = (_Float16)fmaxf(v1.w, 0.f);
        ((half4*)Xth)[r] = h1;
        const float4 v2 = ((const float4*)xd)[r];
        half4 h2;
        h2[0] = (_Float16)fmaxf(v2.x, 0.f); h2[1] = (_Float16)fmaxf(v2.y, 0.f);
        h2[2] = (_Float16)fmaxf(v2.z, 0.f); h2[3] = (_Float16)fmaxf(v2.w, 0.f);
        ((half4*)Xdh)[r] = h2;
    }
    if (bid < 128) {                                  // Wt[n][k] = (half)W[k][n]
        const int which = bid >> 6, t = bid & 63;
        const float* __restrict__ src = which ? Wc : Wp;
        _Float16*    __restrict__ dst = which ? Wct : Wpt;
        const int tx = (t & 7) << 6;                  // k base
        const int ty = (t >> 3) << 6;                 // n base
        const int r0 = tid >> 4;                      // 0..31
        const int c4 = (tid & 15) << 2;               // 0..60
        #pragma unroll
        for (int p = 0; p < 2; ++p) {
            const int kr = r0 + (p << 5);
            const float4 v = *(const float4*)(src + (size_t)(tx + kr) * C_ + ty + c4);
            sm.a.tr[c4 + 0][kr] = (_Float16)v.x;
            sm.a.tr[c4 + 1][kr] = (_Float16)v.y;
            sm.a.tr[c4 + 2][kr] = (_Float16)v.z;
            sm.a.tr[c4 + 3][kr] = (_Float16)v.w;
        }
        __syncthreads();
        const int nr = tid >> 3, k8 = (tid & 7) << 3;
        *(half8*)(dst + (size_t)(ty + nr) * C_ + tx + k8) = *(const half8*)&sm.a.tr[nr][k8];
    }
    grid_barrier(bar, 0);

    // ============ Phase B: projections; wave = (m-tile, 2 n-tiles, shared A) =
    {
        const int which = bid >> 8;
        const int r8 = bid & 255;
        const int m0  = (r8 >> 1) << 4;               // m-tile 0..127
        const int nt0 = ((r8 & 1) << 4) + wv;         // n-tile: nt0 and nt0+8
        const _Float16* __restrict__ Xh = which ? Xdh : Xth;
        const _Float16* __restrict__ Wt = which ? Wct : Wpt;
        const float*    __restrict__ bias = which ? bc : bp;
        _Float16*       __restrict__ Y  = which ? pc : pt;
        const int n0a = nt0 << 4;
        const int n0b = (nt0 + 8) << 4;

        const _Float16* __restrict__ Ap  = Xh + (size_t)(m0 + l15) * C_ + (quad << 3);
        const _Float16* __restrict__ Bpa = Wt + (size_t)(n0a + l15) * C_ + (quad << 3);
        const _Float16* __restrict__ Bpb = Wt + (size_t)(n0b + l15) * C_ + (quad << 3);
        f32x4 acca = {}, accb = {};
        #pragma unroll
        for (int ks = 0; ks < 16; ++ks) {
            half8 af = *(const half8*)(Ap + (ks << 5));
            half8 ba = *(const half8*)(Bpa + (ks << 5));
            acca = __builtin_amdgcn_mfma_f32_16x16x32_f16(af, ba, acca, 0, 0, 0);
            half8 bb = *(const half8*)(Bpb + (ks << 5));
            accb = __builtin_amdgcn_mfma_f32_16x16x32_f16(af, bb, accb, 0, 0, 0);
        }
        const float bza = bias[n0a + l15], bzb = bias[n0b + l15];
        // C/D: col = lane&15 (n), row = quad*4 + r (m)
        #pragma unroll
        for (int r = 0; r < 4; ++r) {
            Y[(size_t)(m0 + (quad << 2) + r) * C_ + n0a + l15] = (_Float16)(acca[r] + bza);
            Y[(size_t)(m0 + (quad << 2) + r) * C_ + n0b + l15] = (_Float16)(accb[r] + bzb);
        }
    }
    grid_barrier(bar, 1);

    // ============ Phase C: 2 tile-tasks/block; scores (split-k MFMA) + tanh ==
    // task t: b = t>>7, i-tile = (t&127)>>3 (16 rows), j-pair = t&7 (32 rows).
    // Single-writer outputs: cpart[t][c], tile_sum[t]. No atomics.
    #pragma unroll 1
    for (int pass = 0; pass < 2; ++pass) {
        const int t  = bid + (pass << 9);
        const int b  = t >> 7;
        const int rm = t & 127;
        const int i0 = (rm >> 3) << 4;
        const int j0 = (rm & 7) << 5;

        // hoisted tanh operands: issue early, consumed after score phase
        const float* __restrict__ xdb = xd + (size_t)(b * L_ + i0) * C_ + tid;
        const float* __restrict__ xtb = xt + (size_t)(b * L_ + j0) * C_ + tid;
        f32x2 xds2[8];                 // 16 xd rows, prescaled by 2*log2(e)
        #pragma unroll
        for (int h = 0; h < 8; ++h) {
            xds2[h].x = xdb[(size_t)(2 * h) * C_]     * 2.8853900817779268f;
            xds2[h].y = xdb[(size_t)(2 * h + 1) * C_] * 2.8853900817779268f;
        }
        float xtv[32];
        #pragma unroll
        for (int j = 0; j < 32; ++j) xtv[j] = xtb[(size_t)j * C_];

        // --- scores: wave wv -> (j-half = wv&1, k-quarter = wv>>1) ---
        {
            const int jh = wv & 1, kq = wv >> 1;
            const _Float16* __restrict__ Ap =
                pt + (size_t)(b * L_ + i0 + l15) * C_ + (kq << 7) + (quad << 3);
            const _Float16* __restrict__ Bp =
                pc + (size_t)(b * L_ + j0 + (jh << 4) + l15) * C_ + (kq << 7) + (quad << 3);
            f32x4 acc = {};
            #pragma unroll
            for (int ks = 0; ks < 4; ++ks) {
                half8 af = *(const half8*)(Ap + (ks << 5));
                half8 bf = *(const half8*)(Bp + (ks << 5));
                acc = __builtin_amdgcn_mfma_f32_16x16x32_f16(af, bf, acc, 0, 0, 0);
            }
            *(f32x4*)&sm.c.red[wv][lane << 2] = acc;
        }
        __syncthreads();               // red ready (prev-pass red readers done at prev S3)
        {
            const int jh2 = tid >> 8, slot = tid & 255;
            const float sc = (sm.c.red[jh2][slot]     + sm.c.red[jh2 + 2][slot]) +
                             (sm.c.red[jh2 + 4][slot] + sm.c.red[jh2 + 6][slot]);
            const float z = sigmoid_fast(sc);
            const int ln = slot >> 2, r = slot & 3;
            // C/D layout: col(j) = ln&15, row(i) = (ln>>4)*4 + r ; store [j][i]
            sm.c.ws[jh2][ln & 15][((ln >> 4) << 2) + r] = z;
            float lsum = z;
            #pragma unroll
            for (int off = 32; off; off >>= 1) lsum += __shfl_xor(lsum, off);
            if (lane == 0) sm.c.wred[wv] = lsum;
        }
        __syncthreads();               // ws + wred ready
        if (tid == 0) {
            float ts = 0.f;
            #pragma unroll
            for (int v = 0; v < 8; ++v) ts += sm.c.wred[v];
            tile_sum[t] = ts;          // single writer
        }

        // --- tanh-r: thread = channel; r = 1/(1+exp2(2*log2e*xd*xt)) ---
        f32x2 acc01 = {0.f, 0.f}, acc23 = {0.f, 0.f};
        #pragma unroll
        for (int jh = 0; jh < 2; ++jh) {
            #pragma unroll
            for (int jj = 0; jj < 16; ++jj) {
                const float xv = xtv[(jh << 4) + jj];
                #pragma unroll
                for (int iq = 0; iq < 4; ++iq) {
                    const float4 w4 = *(const float4*)&sm.c.ws[jh][jj][iq << 2]; // bcast
                    f32x2 x01 = xds2[iq * 2] * xv;                               // v_pk_mul
                    f32x2 e01 = { __builtin_amdgcn_exp2f(x01.x), __builtin_amdgcn_exp2f(x01.y) };
                    f32x2 q01 = e01 + 1.0f;
                    float rp01 = __builtin_amdgcn_rcpf(q01.x * q01.y);
                    f32x2 r01 = rp01 * __builtin_shufflevector(q01, q01, 1, 0);
                    f32x2 w01 = { w4.x, w4.y };
                    acc01 = w01 * r01 + acc01;                                   // v_pk_fma
                    f32x2 x23 = xds2[iq * 2 + 1] * xv;
                    f32x2 e23 = { __builtin_amdgcn_exp2f(x23.x), __builtin_amdgcn_exp2f(x23.y) };
                    f32x2 q23 = e23 + 1.0f;
                    float rp23 = __builtin_amdgcn_rcpf(q23.x * q23.y);
                    f32x2 r23 = rp23 * __builtin_shufflevector(q23, q23, 1, 0);
                    f32x2 w23 = { w4.z, w4.w };
                    acc23 = w23 * r23 + acc23;
                }
            }
        }
        cpart[(size_t)t * C_ + tid] =                  // single writer
            (acc01.x + acc01.y) + (acc23.x + acc23.y);
    }
    grid_barrier(bar, 2);

    // ============ Phase D: deterministic reduce + cp@Wf + bf (64 blocks) =====
    if (bid < 64) {
        const int b = bid >> 3, oc = bid & 7;
        // cp_raw[c] = sum over 128 tiles (fixed order)
        float s = 0.f;
        #pragma unroll 8
        for (int rm = 0; rm < 128; ++rm)
            s += cpart[(size_t)((b << 7) + rm) * C_ + tid];
        // S = sum of 128 tile sums (fixed tree)
        if (tid < 128) sm.d.redf[tid] = tile_sum[(b << 7) + tid];
        __syncthreads();
        for (int st = 64; st > 0; st >>= 1) {
            if (tid < st) sm.d.redf[tid] += sm.d.redf[tid + st];
            __syncthreads();
        }
        const float S = sm.d.redf[0];
        sm.d.cp[tid] = 1.0f - 2.0f * s / S;
        __syncthreads();
        const int o  = (oc << 6) | (tid & 63);
        const int c0 = (tid >> 6) << 6;
        float acc = 0.f;
        #pragma unroll 8
        for (int i = 0; i < 64; ++i) {
            const int cc = c0 + i;
            acc = fmaf(sm.d.cp[cc], Wf[(size_t)cc * OUT_ + o], acc);
        }
        sm.d.redf[tid] = acc;
        __syncthreads();
        if (tid < 64) {
            float a = 0.f;
            #pragma unroll
            for (int g = 0; g < 8; ++g) a += sm.d.redf[(g << 6) | tid];
            out[(size_t)b * OUT_ + ((oc << 6) | tid)] = a + bfv[(oc << 6) | tid];
        }
    }
}

// ---------------------------------------------------------------------------
extern "C" void kernel_launch(void* const* d_in, const int* in_sizes, int n_in,
                              void* d_out, int out_size, void* d_ws, size_t ws_size,
                              hipStream_t stream)
{
    (void)in_sizes; (void)n_in; (void)out_size; (void)ws_size;
    const float* xd = (const float*)d_in[0];
    const float* xt = (const float*)d_in[1];
    const float* Wc = (const float*)d_in[2];
    const float* bc = (const float*)d_in[3];
    const float* Wp = (const float*)d_in[4];
    const float* bp = (const float*)d_in[5];
    const float* Wf = (const float*)d_in[6];
    const float* bf = (const float*)d_in[7];
    float* out = (float*)d_out;

    // workspace layout (~11.3 MB)
    unsigned* bar = (unsigned*)d_ws;                          // 16 u32
    char* p = (char*)d_ws + 4096;
    _Float16* Xth = (_Float16*)p;            p += 2097152;    // 2048x512 f16
    _Float16* Xdh = (_Float16*)p;            p += 2097152;
    _Float16* Wpt = (_Float16*)p;            p += 524288;     // 512x512 f16
    _Float16* Wct = (_Float16*)p;            p += 524288;
    _Float16* pt  = (_Float16*)p;            p += 2097152;
    _Float16* pc  = (_Float16*)p;            p += 2097152;
    float* cpart    = (float*)p;             p += 2097152;    // 1024x512 f32
    float* tile_sum = (float*)p;             p += 4096;       // 1024 f32

    // zero only the barrier counters (everything else is single-writer)
    hipMemsetAsync(d_ws, 0, 64, stream);
    mega_kernel<<<NB, NT, 0, stream>>>(xd, xt, Wc, bc, Wp, bp, Wf, bf,
                                       bar, Xth, Xdh, Wpt, Wct, pt, pc,
                                       cpart, tile_sum, out);
}

// Round 5
// 156.500 us; speedup vs baseline: 2.0166x; 2.0166x over previous
//
#include <hip/hip_runtime.h>
#include <math.h>

// Problem constants
#define B_   8
#define L_   256
#define C_   512
#define OUT_ 512

typedef _Float16 half8 __attribute__((ext_vector_type(8)));
typedef _Float16 half4 __attribute__((ext_vector_type(4)));
typedef float    f32x4 __attribute__((ext_vector_type(4)));
typedef float    f32x2 __attribute__((ext_vector_type(2)));

// ---------------------------------------------------------------------------
// Kernel 1: MFMA relu-GEMM projections (R0-proven version, verbatim).
//   Y[m][n] = sum_k relu(X[m][k]) * W[k][n] + bias[n],  W raw f32 [k][n].
// 64x64 tile, KT=32, LDS double-buffer, 1 barrier/step. grid (8,32,2), 256thr.
// ---------------------------------------------------------------------------
__global__ __launch_bounds__(256)
void proj_mfma_kernel(const float* __restrict__ xt, const float* __restrict__ Wp,
                      const float* __restrict__ bp,
                      const float* __restrict__ xd, const float* __restrict__ Wc,
                      const float* __restrict__ bc,
                      _Float16* __restrict__ pt, _Float16* __restrict__ pc)
{
    const int which = blockIdx.z;
    const float* __restrict__ X    = which ? xd : xt;
    const float* __restrict__ W    = which ? Wc : Wp;
    const float* __restrict__ bias = which ? bc : bp;
    _Float16*    __restrict__ Y    = which ? pc : pt;

    __shared__ _Float16 Ah[2][64][40];   // [buf][m][k]
    __shared__ _Float16 Bh[2][64][40];   // [buf][n][k]
    __shared__ _Float16 Ot[64][72];

    const int tid = threadIdx.x;
    const int m0 = blockIdx.y << 6, n0 = blockIdx.x << 6;
    const int lane = tid & 63, wv = tid >> 6;
    const int l15 = lane & 15, quad = lane >> 4;

    const int srow = tid >> 2, sch = (tid & 3) << 3;
    const float* Ag = X + (size_t)(m0 + srow) * C_ + sch;
    const int nl = tid & 63, kseg = tid >> 6;
    const float* Bg = W + (size_t)(kseg << 3) * C_ + n0 + nl;

    float4 a0 = *(const float4*)(Ag);
    float4 a1 = *(const float4*)(Ag + 4);
    float wr[8];
    #pragma unroll
    for (int r = 0; r < 8; ++r) wr[r] = Bg[(size_t)r * C_];

    {
        half8 av;
        av[0] = (_Float16)fmaxf(a0.x, 0.f); av[1] = (_Float16)fmaxf(a0.y, 0.f);
        av[2] = (_Float16)fmaxf(a0.z, 0.f); av[3] = (_Float16)fmaxf(a0.w, 0.f);
        av[4] = (_Float16)fmaxf(a1.x, 0.f); av[5] = (_Float16)fmaxf(a1.y, 0.f);
        av[6] = (_Float16)fmaxf(a1.z, 0.f); av[7] = (_Float16)fmaxf(a1.w, 0.f);
        *(half8*)&Ah[0][srow][sch] = av;
        half8 bv;
        #pragma unroll
        for (int r = 0; r < 8; ++r) bv[r] = (_Float16)wr[r];
        *(half8*)&Bh[0][nl][kseg << 3] = bv;
    }

    f32x4 acc[4] = {};
    for (int ks = 0; ks < 16; ++ks) {
        const int cur = ks & 1;
        if (ks < 15) {
            Ag += 32;
            Bg += 32 * C_;
            a0 = *(const float4*)(Ag);
            a1 = *(const float4*)(Ag + 4);
            #pragma unroll
            for (int r = 0; r < 8; ++r) wr[r] = Bg[(size_t)r * C_];
        }
        __syncthreads();
        half8 af = *(const half8*)&Ah[cur][(wv << 4) + l15][quad << 3];
        #pragma unroll
        for (int nb = 0; nb < 4; ++nb) {
            half8 bf = *(const half8*)&Bh[cur][(nb << 4) + l15][quad << 3];
            acc[nb] = __builtin_amdgcn_mfma_f32_16x16x32_f16(af, bf, acc[nb], 0, 0, 0);
        }
        if (ks < 15) {
            half8 av;
            av[0] = (_Float16)fmaxf(a0.x, 0.f); av[1] = (_Float16)fmaxf(a0.y, 0.f);
            av[2] = (_Float16)fmaxf(a0.z, 0.f); av[3] = (_Float16)fmaxf(a0.w, 0.f);
            av[4] = (_Float16)fmaxf(a1.x, 0.f); av[5] = (_Float16)fmaxf(a1.y, 0.f);
            av[6] = (_Float16)fmaxf(a1.z, 0.f); av[7] = (_Float16)fmaxf(a1.w, 0.f);
            *(half8*)&Ah[cur ^ 1][srow][sch] = av;
            half8 bv;
            #pragma unroll
            for (int r = 0; r < 8; ++r) bv[r] = (_Float16)wr[r];
            *(half8*)&Bh[cur ^ 1][nl][kseg << 3] = bv;
        }
    }

    __syncthreads();
    #pragma unroll
    for (int nb = 0; nb < 4; ++nb) {
        const float bz = bias[n0 + (nb << 4) + l15];
        #pragma unroll
        for (int r = 0; r < 4; ++r)
            Ot[(wv << 4) + (quad << 2) + r][(nb << 4) + l15] = (_Float16)(acc[nb][r] + bz);
    }
    __syncthreads();
    const int erow = tid >> 3, ech = (tid & 7) << 3;
    #pragma unroll
    for (int h = 0; h < 64; h += 32)
        *(half8*)&Y[(size_t)(m0 + erow + h) * C_ + n0 + ech] = *(const half8*)&Ot[erow + h][ech];
}

// ---------------------------------------------------------------------------
__device__ __forceinline__ float sigmoid_fast(float z) {
    float e = __builtin_amdgcn_exp2f(-1.4426950408889634f * z);
    return __builtin_amdgcn_rcpf(e + 1.0f);
}

// ---------------------------------------------------------------------------
// Kernel 2 (FUSED, v3): per 16x32 (i,j) tile: scores via 8-wave split-k MFMA
// (2 j-halves x 4 k-quarters, LDS reduce) + sigmoid -> ws LDS + tile_sum;
// then weighted tanh-r accumulation (thread = channel), single-writer cpart.
// This phase body is byte-identical to R4's phase C, which passed correctness
// (incl. replay determinism) inside the mega-kernel; here it runs at 1024
// blocks = 4 blocks/CU (LB(512,8) -> <=64 VGPR; R4 superset compiled to 60)
// instead of R0's 2 blocks/CU with half the waves idle during MFMA.
// grid (128, 8) x 512 thr. No atomics anywhere.
// ---------------------------------------------------------------------------
__global__ __launch_bounds__(512, 8)
void cp_tanh_kernel(const _Float16* __restrict__ pt, const _Float16* __restrict__ pc,
                    const float* __restrict__ xd, const float* __restrict__ xt,
                    float* __restrict__ cpart, float* __restrict__ tile_sum)
{
    const int rm = blockIdx.x;            // tile 0..127
    const int b  = blockIdx.y;
    const int i0 = (rm >> 3) << 4;        // 16 i-rows
    const int j0 = (rm & 7) << 5;         // 32 j-rows
    const int tid = threadIdx.x;
    const int wv = tid >> 6, lane = tid & 63;
    const int l15 = lane & 15, quad = lane >> 4;

    __shared__ float red[8][256];         // 8 KB: split-k partial C tiles
    __shared__ float ws[2][16][20];       // [j-half][j][i] sigmoid weights
    __shared__ float wred[8];

    // hoisted tanh operands (issued early; consumed after score phase)
    const float* __restrict__ xdb = xd + (size_t)(b * L_ + i0) * C_ + tid;
    const float* __restrict__ xtb = xt + (size_t)(b * L_ + j0) * C_ + tid;
    f32x2 xds2[8];                        // 16 xd rows, prescaled by 2*log2(e)
    #pragma unroll
    for (int h = 0; h < 8; ++h) {
        xds2[h].x = xdb[(size_t)(2 * h) * C_]     * 2.8853900817779268f;
        xds2[h].y = xdb[(size_t)(2 * h + 1) * C_] * 2.8853900817779268f;
    }
    float xtv[32];
    #pragma unroll
    for (int j = 0; j < 32; ++j) xtv[j] = xtb[(size_t)j * C_];

    // --- scores: wave wv -> (j-half = wv&1, k-quarter = wv>>1), K=128 each ---
    {
        const int jh = wv & 1, kq = wv >> 1;
        const _Float16* __restrict__ Ap =
            pt + (size_t)(b * L_ + i0 + l15) * C_ + (kq << 7) + (quad << 3);
        const _Float16* __restrict__ Bp =
            pc + (size_t)(b * L_ + j0 + (jh << 4) + l15) * C_ + (kq << 7) + (quad << 3);
        f32x4 acc = {};
        #pragma unroll
        for (int ks = 0; ks < 4; ++ks) {
            half8 af = *(const half8*)(Ap + (ks << 5));
            half8 bf = *(const half8*)(Bp + (ks << 5));
            acc = __builtin_amdgcn_mfma_f32_16x16x32_f16(af, bf, acc, 0, 0, 0);
        }
        *(f32x4*)&red[wv][lane << 2] = acc;
    }
    __syncthreads();
    {
        const int jh2 = tid >> 8, slot = tid & 255;
        const float sc = (red[jh2][slot]     + red[jh2 + 2][slot]) +
                         (red[jh2 + 4][slot] + red[jh2 + 6][slot]);
        const float z = sigmoid_fast(sc);
        const int ln = slot >> 2, r = slot & 3;
        // C/D layout: col(j) = ln&15, row(i) = (ln>>4)*4 + r ; store [j][i]
        ws[jh2][ln & 15][((ln >> 4) << 2) + r] = z;
        float lsum = z;
        #pragma unroll
        for (int off = 32; off; off >>= 1) lsum += __shfl_xor(lsum, off);
        if (lane == 0) wred[wv] = lsum;
    }
    __syncthreads();                      // ws + wred ready
    if (tid == 0) {
        float ts = 0.f;
        #pragma unroll
        for (int v = 0; v < 8; ++v) ts += wred[v];
        tile_sum[(b << 7) | rm] = ts;     // single writer, fixed order
    }

    // --- tanh-r: thread = channel; r = 1/(1+exp2(2*log2e*xd*xt)) ------------
    f32x2 acc01 = {0.f, 0.f}, acc23 = {0.f, 0.f};
    #pragma unroll
    for (int jh = 0; jh < 2; ++jh) {
        #pragma unroll
        for (int jj = 0; jj < 16; ++jj) {
            const float xv = xtv[(jh << 4) + jj];
            #pragma unroll
            for (int iq = 0; iq < 4; ++iq) {
                const float4 w4 = *(const float4*)&ws[jh][jj][iq << 2];  // bcast
                f32x2 x01 = xds2[iq * 2] * xv;                           // v_pk_mul
                f32x2 e01 = { __builtin_amdgcn_exp2f(x01.x), __builtin_amdgcn_exp2f(x01.y) };
                f32x2 q01 = e01 + 1.0f;
                float rp01 = __builtin_amdgcn_rcpf(q01.x * q01.y);
                f32x2 r01 = rp01 * __builtin_shufflevector(q01, q01, 1, 0);
                f32x2 w01 = { w4.x, w4.y };
                acc01 = w01 * r01 + acc01;                               // v_pk_fma
                f32x2 x23 = xds2[iq * 2 + 1] * xv;
                f32x2 e23 = { __builtin_amdgcn_exp2f(x23.x), __builtin_amdgcn_exp2f(x23.y) };
                f32x2 q23 = e23 + 1.0f;
                float rp23 = __builtin_amdgcn_rcpf(q23.x * q23.y);
                f32x2 r23 = rp23 * __builtin_shufflevector(q23, q23, 1, 0);
                f32x2 w23 = { w4.z, w4.w };
                acc23 = w23 * r23 + acc23;
            }
        }
    }
    cpart[(size_t)((b << 7) | rm) * C_ + tid] =      // single writer
        (acc01.x + acc01.y) + (acc23.x + acc23.y);
}

// ---------------------------------------------------------------------------
// Kernel 3: deterministic reduce of 128 tiles/b + cp = 1-2s/S + out = cp@Wf+bf
// grid (8,8) [x = out-chunk, y = b], 512 thr. (R4 phase D logic, proven.)
// ---------------------------------------------------------------------------
__global__ __launch_bounds__(512)
void finalize_kernel(const float* __restrict__ cpart, const float* __restrict__ tile_sum,
                     const float* __restrict__ Wf, const float* __restrict__ bfv,
                     float* __restrict__ out)
{
    const int oc = blockIdx.x, b = blockIdx.y;
    const int tid = threadIdx.x;
    __shared__ float cp[C_];
    __shared__ float redf[512];

    // cp_raw[c] = sum over 128 tiles (fixed order)
    float s = 0.f;
    #pragma unroll 8
    for (int rm = 0; rm < 128; ++rm)
        s += cpart[(size_t)((b << 7) + rm) * C_ + tid];

    // S = sum of 128 tile sums (fixed tree)
    if (tid < 128) redf[tid] = tile_sum[(b << 7) + tid];
    __syncthreads();
    for (int st = 64; st > 0; st >>= 1) {
        if (tid < st) redf[tid] += redf[tid + st];
        __syncthreads();
    }
    const float S = redf[0];
    cp[tid] = 1.0f - 2.0f * s / S;
    __syncthreads();

    const int o  = (oc << 6) | (tid & 63);
    const int c0 = (tid >> 6) << 6;
    float acc = 0.f;
    #pragma unroll 8
    for (int i = 0; i < 64; ++i) {
        const int cc = c0 + i;
        acc = fmaf(cp[cc], Wf[(size_t)cc * OUT_ + o], acc);
    }
    redf[tid] = acc;
    __syncthreads();
    if (tid < 64) {
        float a = 0.f;
        #pragma unroll
        for (int g = 0; g < 8; ++g) a += redf[(g << 6) | tid];
        out[(size_t)b * OUT_ + ((oc << 6) | tid)] = a + bfv[(oc << 6) | tid];
    }
}

// ---------------------------------------------------------------------------
extern "C" void kernel_launch(void* const* d_in, const int* in_sizes, int n_in,
                              void* d_out, int out_size, void* d_ws, size_t ws_size,
                              hipStream_t stream)
{
    (void)in_sizes; (void)n_in; (void)out_size; (void)ws_size;
    const float* xd = (const float*)d_in[0];
    const float* xt = (const float*)d_in[1];
    const float* Wc = (const float*)d_in[2];
    const float* bc = (const float*)d_in[3];
    const float* Wp = (const float*)d_in[4];
    const float* bp = (const float*)d_in[5];
    const float* Wf = (const float*)d_in[6];
    const float* bf = (const float*)d_in[7];
    float* out = (float*)d_out;

    // workspace (~6 MB), all single-writer -> no memset needed
    _Float16* pt = (_Float16*)d_ws;                  // 2048x512 f16 = 2 MB
    _Float16* pc = pt + 1048576;                     // 2 MB
    float* cpart    = (float*)(pc + 1048576);        // 1024x512 f32 = 2 MB
    float* tile_sum = cpart + 524288;                // 1024 f32

    proj_mfma_kernel<<<dim3(8, 32, 2), 256, 0, stream>>>(xt, Wp, bp, xd, Wc, bc, pt, pc);
    cp_tanh_kernel<<<dim3(128, 8), 512, 0, stream>>>(pt, pc, xd, xt, cpart, tile_sum);
    finalize_kernel<<<dim3(8, 8), 512, 0, stream>>>(cpart, tile_sum, Wf, bf, out);
}

// Round 6
// 137.270 us; speedup vs baseline: 2.2992x; 1.1401x over previous
//
#include <hip/hip_runtime.h>
#include <math.h>

// Problem constants
#define B_   8
#define L_   256
#define C_   512
#define OUT_ 512

typedef _Float16 half8 __attribute__((ext_vector_type(8)));
typedef _Float16 half4 __attribute__((ext_vector_type(4)));
typedef float    f32x4 __attribute__((ext_vector_type(4)));
typedef float    f32x2 __attribute__((ext_vector_type(2)));

// ---------------------------------------------------------------------------
// Kernel 1: MFMA relu-GEMM projections (R0-proven version, verbatim).
//   Y[m][n] = sum_k relu(X[m][k]) * W[k][n] + bias[n],  W raw f32 [k][n].
// 64x64 tile, KT=32, LDS double-buffer, 1 barrier/step. grid (8,32,2), 256thr.
// ---------------------------------------------------------------------------
__global__ __launch_bounds__(256)
void proj_mfma_kernel(const float* __restrict__ xt, const float* __restrict__ Wp,
                      const float* __restrict__ bp,
                      const float* __restrict__ xd, const float* __restrict__ Wc,
                      const float* __restrict__ bc,
                      _Float16* __restrict__ pt, _Float16* __restrict__ pc)
{
    const int which = blockIdx.z;
    const float* __restrict__ X    = which ? xd : xt;
    const float* __restrict__ W    = which ? Wc : Wp;
    const float* __restrict__ bias = which ? bc : bp;
    _Float16*    __restrict__ Y    = which ? pc : pt;

    __shared__ _Float16 Ah[2][64][40];   // [buf][m][k]
    __shared__ _Float16 Bh[2][64][40];   // [buf][n][k]
    __shared__ _Float16 Ot[64][72];

    const int tid = threadIdx.x;
    const int m0 = blockIdx.y << 6, n0 = blockIdx.x << 6;
    const int lane = tid & 63, wv = tid >> 6;
    const int l15 = lane & 15, quad = lane >> 4;

    const int srow = tid >> 2, sch = (tid & 3) << 3;
    const float* Ag = X + (size_t)(m0 + srow) * C_ + sch;
    const int nl = tid & 63, kseg = tid >> 6;
    const float* Bg = W + (size_t)(kseg << 3) * C_ + n0 + nl;

    float4 a0 = *(const float4*)(Ag);
    float4 a1 = *(const float4*)(Ag + 4);
    float wr[8];
    #pragma unroll
    for (int r = 0; r < 8; ++r) wr[r] = Bg[(size_t)r * C_];

    {
        half8 av;
        av[0] = (_Float16)fmaxf(a0.x, 0.f); av[1] = (_Float16)fmaxf(a0.y, 0.f);
        av[2] = (_Float16)fmaxf(a0.z, 0.f); av[3] = (_Float16)fmaxf(a0.w, 0.f);
        av[4] = (_Float16)fmaxf(a1.x, 0.f); av[5] = (_Float16)fmaxf(a1.y, 0.f);
        av[6] = (_Float16)fmaxf(a1.z, 0.f); av[7] = (_Float16)fmaxf(a1.w, 0.f);
        *(half8*)&Ah[0][srow][sch] = av;
        half8 bv;
        #pragma unroll
        for (int r = 0; r < 8; ++r) bv[r] = (_Float16)wr[r];
        *(half8*)&Bh[0][nl][kseg << 3] = bv;
    }

    f32x4 acc[4] = {};
    for (int ks = 0; ks < 16; ++ks) {
        const int cur = ks & 1;
        if (ks < 15) {
            Ag += 32;
            Bg += 32 * C_;
            a0 = *(const float4*)(Ag);
            a1 = *(const float4*)(Ag + 4);
            #pragma unroll
            for (int r = 0; r < 8; ++r) wr[r] = Bg[(size_t)r * C_];
        }
        __syncthreads();
        half8 af = *(const half8*)&Ah[cur][(wv << 4) + l15][quad << 3];
        #pragma unroll
        for (int nb = 0; nb < 4; ++nb) {
            half8 bf = *(const half8*)&Bh[cur][(nb << 4) + l15][quad << 3];
            acc[nb] = __builtin_amdgcn_mfma_f32_16x16x32_f16(af, bf, acc[nb], 0, 0, 0);
        }
        if (ks < 15) {
            half8 av;
            av[0] = (_Float16)fmaxf(a0.x, 0.f); av[1] = (_Float16)fmaxf(a0.y, 0.f);
            av[2] = (_Float16)fmaxf(a0.z, 0.f); av[3] = (_Float16)fmaxf(a0.w, 0.f);
            av[4] = (_Float16)fmaxf(a1.x, 0.f); av[5] = (_Float16)fmaxf(a1.y, 0.f);
            av[6] = (_Float16)fmaxf(a1.z, 0.f); av[7] = (_Float16)fmaxf(a1.w, 0.f);
            *(half8*)&Ah[cur ^ 1][srow][sch] = av;
            half8 bv;
            #pragma unroll
            for (int r = 0; r < 8; ++r) bv[r] = (_Float16)wr[r];
            *(half8*)&Bh[cur ^ 1][nl][kseg << 3] = bv;
        }
    }

    __syncthreads();
    #pragma unroll
    for (int nb = 0; nb < 4; ++nb) {
        const float bz = bias[n0 + (nb << 4) + l15];
        #pragma unroll
        for (int r = 0; r < 4; ++r)
            Ot[(wv << 4) + (quad << 2) + r][(nb << 4) + l15] = (_Float16)(acc[nb][r] + bz);
    }
    __syncthreads();
    const int erow = tid >> 3, ech = (tid & 7) << 3;
    #pragma unroll
    for (int h = 0; h < 64; h += 32)
        *(half8*)&Y[(size_t)(m0 + erow + h) * C_ + n0 + ech] = *(const half8*)&Ot[erow + h][ech];
}

// ---------------------------------------------------------------------------
__device__ __forceinline__ float sigmoid_fast(float z) {
    float e = __builtin_amdgcn_exp2f(-1.4426950408889634f * z);
    return __builtin_amdgcn_rcpf(e + 1.0f);
}

// ---------------------------------------------------------------------------
// Kernel 2 (FUSED, v4): per 16x32 (i,j) tile: scores via 8-wave split-k MFMA
// + sigmoid -> ws LDS + tile_sum; then weighted tanh-r (thread = channel).
// v4 vs v3 (spill fix): LB(512,4) -- R5's LB(512,8) forced VGPR=32 and the
// compiler spilled ~30 regs/thread to scratch (FETCH 60.6MB vs 19.5 ideal,
// WRITE 67.6MB vs 2.1 actual). R4 proved this body fits 60 VGPR at LB(512,4);
// occupancy follows ACTUAL vgpr (<=64 -> 4 blocks/CU), so nothing is lost.
// Loads restructured to shrink live ranges: xd/xt loaded AFTER score phase,
// xt in 16-value halves inside an unroll-1 loop (peak live ~50 regs).
// grid (128, 8) x 512 thr. No atomics; single-writer outputs.
// ---------------------------------------------------------------------------
__global__ __launch_bounds__(512, 4)
void cp_tanh_kernel(const _Float16* __restrict__ pt, const _Float16* __restrict__ pc,
                    const float* __restrict__ xd, const float* __restrict__ xt,
                    float* __restrict__ cpart, float* __restrict__ tile_sum)
{
    const int rm = blockIdx.x;            // tile 0..127
    const int b  = blockIdx.y;
    const int i0 = (rm >> 3) << 4;        // 16 i-rows
    const int j0 = (rm & 7) << 5;         // 32 j-rows
    const int tid = threadIdx.x;
    const int wv = tid >> 6, lane = tid & 63;
    const int l15 = lane & 15, quad = lane >> 4;

    __shared__ float red[8][256];         // 8 KB: split-k partial C tiles
    __shared__ float ws[2][16][20];       // [j-half][j][i] sigmoid weights
    __shared__ float wred[8];

    // --- scores: wave wv -> (j-half = wv&1, k-quarter = wv>>1), K=128 each ---
    {
        const int jh = wv & 1, kq = wv >> 1;
        const _Float16* __restrict__ Ap =
            pt + (size_t)(b * L_ + i0 + l15) * C_ + (kq << 7) + (quad << 3);
        const _Float16* __restrict__ Bp =
            pc + (size_t)(b * L_ + j0 + (jh << 4) + l15) * C_ + (kq << 7) + (quad << 3);
        f32x4 acc = {};
        #pragma unroll
        for (int ks = 0; ks < 4; ++ks) {
            half8 af = *(const half8*)(Ap + (ks << 5));
            half8 bf = *(const half8*)(Bp + (ks << 5));
            acc = __builtin_amdgcn_mfma_f32_16x16x32_f16(af, bf, acc, 0, 0, 0);
        }
        *(f32x4*)&red[wv][lane << 2] = acc;
    }
    __syncthreads();
    {
        const int jh2 = tid >> 8, slot = tid & 255;
        const float sc = (red[jh2][slot]     + red[jh2 + 2][slot]) +
                         (red[jh2 + 4][slot] + red[jh2 + 6][slot]);
        const float z = sigmoid_fast(sc);
        const int ln = slot >> 2, r = slot & 3;
        // C/D layout: col(j) = ln&15, row(i) = (ln>>4)*4 + r ; store [j][i]
        ws[jh2][ln & 15][((ln >> 4) << 2) + r] = z;
        float lsum = z;
        #pragma unroll
        for (int off = 32; off; off >>= 1) lsum += __shfl_xor(lsum, off);
        if (lane == 0) wred[wv] = lsum;
    }
    __syncthreads();                      // ws + wred ready
    if (tid == 0) {
        float ts = 0.f;
        #pragma unroll
        for (int v = 0; v < 8; ++v) ts += wred[v];
        tile_sum[(b << 7) | rm] = ts;     // single writer, fixed order
    }

    // --- tanh-r: thread = channel; r = 1/(1+exp2(2*log2e*xd*xt)) ------------
    // loads AFTER the score phase (short live ranges; TLP hides latency)
    const float* __restrict__ xdb = xd + (size_t)(b * L_ + i0) * C_ + tid;
    const float* __restrict__ xtb = xt + (size_t)(b * L_ + j0) * C_ + tid;
    f32x2 xds2[8];                        // 16 xd rows, prescaled by 2*log2(e)
    #pragma unroll
    for (int h = 0; h < 8; ++h) {
        xds2[h].x = xdb[(size_t)(2 * h) * C_]     * 2.8853900817779268f;
        xds2[h].y = xdb[(size_t)(2 * h + 1) * C_] * 2.8853900817779268f;
    }

    f32x2 acc01 = {0.f, 0.f}, acc23 = {0.f, 0.f};
    #pragma unroll 1
    for (int jh = 0; jh < 2; ++jh) {      // unroll 1: keeps xtv at 16 live regs
        float xtv[16];
        #pragma unroll
        for (int jj = 0; jj < 16; ++jj)
            xtv[jj] = xtb[(size_t)((jh << 4) + jj) * C_];
        #pragma unroll
        for (int jj = 0; jj < 16; ++jj) {
            const float xv = xtv[jj];
            #pragma unroll
            for (int iq = 0; iq < 4; ++iq) {
                const float4 w4 = *(const float4*)&ws[jh][jj][iq << 2];  // bcast
                f32x2 x01 = xds2[iq * 2] * xv;                           // v_pk_mul
                f32x2 e01 = { __builtin_amdgcn_exp2f(x01.x), __builtin_amdgcn_exp2f(x01.y) };
                f32x2 q01 = e01 + 1.0f;
                float rp01 = __builtin_amdgcn_rcpf(q01.x * q01.y);
                f32x2 r01 = rp01 * __builtin_shufflevector(q01, q01, 1, 0);
                f32x2 w01 = { w4.x, w4.y };
                acc01 = w01 * r01 + acc01;                               // v_pk_fma
                f32x2 x23 = xds2[iq * 2 + 1] * xv;
                f32x2 e23 = { __builtin_amdgcn_exp2f(x23.x), __builtin_amdgcn_exp2f(x23.y) };
                f32x2 q23 = e23 + 1.0f;
                float rp23 = __builtin_amdgcn_rcpf(q23.x * q23.y);
                f32x2 r23 = rp23 * __builtin_shufflevector(q23, q23, 1, 0);
                f32x2 w23 = { w4.z, w4.w };
                acc23 = w23 * r23 + acc23;
            }
        }
    }
    cpart[(size_t)((b << 7) | rm) * C_ + tid] =      // single writer
        (acc01.x + acc01.y) + (acc23.x + acc23.y);
}

// ---------------------------------------------------------------------------
// Kernel 3 (v2): deterministic reduce + cp = 1-2s/S + out = cp@Wf + bf.
// grid (16,8) [x = 32-out chunk, y = b], 512 thr — 2x blocks vs R5 (was
// 2 waves/CU, latency-bound on the 128-load reduce; s-loop redundancy is
// L2-resident and cheap).
// ---------------------------------------------------------------------------
__global__ __launch_bounds__(512)
void finalize_kernel(const float* __restrict__ cpart, const float* __restrict__ tile_sum,
                     const float* __restrict__ Wf, const float* __restrict__ bfv,
                     float* __restrict__ out)
{
    const int oc = blockIdx.x, b = blockIdx.y;
    const int tid = threadIdx.x;
    __shared__ float cp[C_];
    __shared__ float redf[512];

    // cp_raw[c] = sum over 128 tiles (fixed order)
    float s = 0.f;
    #pragma unroll 8
    for (int rm = 0; rm < 128; ++rm)
        s += cpart[(size_t)((b << 7) + rm) * C_ + tid];

    // S = sum of 128 tile sums (fixed tree)
    if (tid < 128) redf[tid] = tile_sum[(b << 7) + tid];
    __syncthreads();
    for (int st = 64; st > 0; st >>= 1) {
        if (tid < st) redf[tid] += redf[tid + st];
        __syncthreads();
    }
    const float S = redf[0];
    cp[tid] = 1.0f - 2.0f * s / S;
    __syncthreads();

    const int o = (oc << 5) | (tid & 31);         // 32 outputs per block
    const int c0 = (tid >> 5) << 5;               // 16 c-groups of 32
    float acc = 0.f;
    #pragma unroll 8
    for (int i = 0; i < 32; ++i) {
        const int cc = c0 + i;
        acc = fmaf(cp[cc], Wf[(size_t)cc * OUT_ + o], acc);
    }
    redf[tid] = acc;
    __syncthreads();
    if (tid < 32) {
        float a = 0.f;
        #pragma unroll
        for (int g = 0; g < 16; ++g) a += redf[(g << 5) | tid];
        out[(size_t)b * OUT_ + ((oc << 5) | tid)] = a + bfv[(oc << 5) | tid];
    }
}

// ---------------------------------------------------------------------------
extern "C" void kernel_launch(void* const* d_in, const int* in_sizes, int n_in,
                              void* d_out, int out_size, void* d_ws, size_t ws_size,
                              hipStream_t stream)
{
    (void)in_sizes; (void)n_in; (void)out_size; (void)ws_size;
    const float* xd = (const float*)d_in[0];
    const float* xt = (const float*)d_in[1];
    const float* Wc = (const float*)d_in[2];
    const float* bc = (const float*)d_in[3];
    const float* Wp = (const float*)d_in[4];
    const float* bp = (const float*)d_in[5];
    const float* Wf = (const float*)d_in[6];
    const float* bf = (const float*)d_in[7];
    float* out = (float*)d_out;

    // workspace (~6 MB), all single-writer -> no memset needed
    _Float16* pt = (_Float16*)d_ws;                  // 2048x512 f16 = 2 MB
    _Float16* pc = pt + 1048576;                     // 2 MB
    float* cpart    = (float*)(pc + 1048576);        // 1024x512 f32 = 2 MB
    float* tile_sum = cpart + 524288;                // 1024 f32

    proj_mfma_kernel<<<dim3(8, 32, 2), 256, 0, stream>>>(xt, Wp, bp, xd, Wc, bc, pt, pc);
    cp_tanh_kernel<<<dim3(128, 8), 512, 0, stream>>>(pt, pc, xd, xt, cpart, tile_sum);
    finalize_kernel<<<dim3(16, 8), 512, 0, stream>>>(cpart, tile_sum, Wf, bf, out);
}